// Round 1
// baseline (334.184 us; speedup 1.0000x reference)
//
#include <hip/hip_runtime.h>
#include <hip/hip_bf16.h>

typedef __attribute__((ext_vector_type(4))) float f32x4;
typedef __attribute__((ext_vector_type(8))) short s16x8;

#define X_ELEMS 25690112          // 32*64*112*112
#define NG_FULL 713614            // X_ELEMS/36 (rem 8)
#define NG      713615
#define HW 112
#define CHW (64*112*112)          // 802816

// q = I * 2^(e-7), |I|<=256 -> exactly representable in bf16; low 16 fp32 bits are 0.
__device__ __forceinline__ unsigned short f32_to_bf16_exact(float q) {
    return (unsigned short)(__float_as_uint(q) >> 16);
}

__device__ __forceinline__ void scale_from_max(float m, float& scale, float& inv) {
    if (m > 0.f) {
        int e = (int)((__float_as_uint(m) >> 23) & 0xFF) - 127;  // exact floor(log2(m)) for normal m
        scale = __builtin_ldexpf(1.0f, e - 7);
        inv   = __builtin_ldexpf(1.0f, 7 - e);
    } else { scale = 0.f; inv = 0.f; }   // all-zero group -> q = 0
}

// ---- Q1: per-group (36 consecutive NCHW elems) scale for x ----
__global__ __launch_bounds__(256) void q1_scales(const float* __restrict__ x,
                                                 float2* __restrict__ sc) {
    int g = blockIdx.x * 256 + threadIdx.x;
    if (g >= NG) return;
    const float4* p = (const float4*)x + g * 9;   // group start is 144B-aligned
    float m = 0.f;
    int nv = (g < NG_FULL) ? 9 : 2;               // tail group: 8 real elems
    for (int i = 0; i < nv; ++i) {
        float4 v = p[i];
        m = fmaxf(m, fmaxf(fmaxf(fabsf(v.x), fabsf(v.y)), fmaxf(fabsf(v.z), fabsf(v.w))));
    }
    float s, inv; scale_from_max(m, s, inv);
    sc[g] = make_float2(s, inv);
}

// ---- QW: quantize weight, write [pos=9][k=64][c=64] bf16 ----
__global__ __launch_bounds__(256) void qw_kernel(const float* __restrict__ w,
                                                 unsigned short* __restrict__ wt) {
    int g = blockIdx.x * 256 + threadIdx.x;
    if (g >= 1024) return;                        // 36864/36 = 1024 exact
    const float4* p = (const float4*)w + g * 9;
    float vv[36]; float m = 0.f;
    #pragma unroll
    for (int i = 0; i < 9; ++i) {
        float4 v = p[i];
        vv[i*4+0]=v.x; vv[i*4+1]=v.y; vv[i*4+2]=v.z; vv[i*4+3]=v.w;
        m = fmaxf(m, fmaxf(fmaxf(fabsf(v.x), fabsf(v.y)), fmaxf(fabsf(v.z), fabsf(v.w))));
    }
    float s, inv; scale_from_max(m, s, inv);
    #pragma unroll
    for (int j = 0; j < 36; ++j) {
        int flat = g * 36 + j;
        int k = flat / 576, rem = flat % 576;
        int c = rem / 9, pp = rem % 9;
        float q = rintf(vv[j] * inv) * s;
        wt[pp * 4096 + k * 64 + c] = f32_to_bf16_exact(q);
    }
}

// ---- Q2: quantize x + transpose NCHW -> NHWC bf16 (per (n,h) row-slab) ----
__global__ __launch_bounds__(256) void q2_transpose(const float* __restrict__ x,
                                                    const float2* __restrict__ sc,
                                                    unsigned short* __restrict__ xt) {
    __shared__ unsigned short lq[64][116];        // [c][w], pad to 116 for alignment
    int n = blockIdx.y, h = blockIdx.x, tid = threadIdx.x;
    int base = n * CHW + h * HW;                  // elem idx of (n, c=0, h, w=0)
    // phase 1: coalesced read along w, quantize, stage [c][w]
    #pragma unroll
    for (int it = 0; it < 7; ++it) {
        int idx4 = it * 256 + tid;                // 0..1791 float4s of [64][112]
        int c = idx4 / 28, w = (idx4 % 28) * 4;
        int off = base + c * 12544 + w;
        float4 v = *(const float4*)(x + off);
        int g0 = off / 36, r = off % 36;
        float2 s0 = sc[g0];
        float vv[4] = {v.x, v.y, v.z, v.w};
        union { unsigned short u[4]; uint2 d; } pk;
        #pragma unroll
        for (int j = 0; j < 4; ++j) {
            float2 sg = (r + j < 36) ? s0 : sc[g0 + 1];
            pk.u[j] = f32_to_bf16_exact(rintf(vv[j] * sg.y) * sg.x);
        }
        *(uint2*)&lq[c][w] = pk.d;
    }
    __syncthreads();
    // phase 2: write NHWC-contiguous 16B chunks (8 c's per chunk)
    int obase = (n * HW + h) * 7168;              // elem idx in xt
    #pragma unroll
    for (int it = 0; it < 4; ++it) {
        int chunk = it * 256 + tid;               // 0..895
        if (chunk < 896) {
            int w = chunk >> 3, c0 = (chunk & 7) * 8;
            union { unsigned short u[8]; uint4 d; } pk;
            #pragma unroll
            for (int j = 0; j < 8; ++j) pk.u[j] = lq[c0 + j][w];
            *(uint4*)(xt + obase + chunk * 8) = pk.d;
        }
    }
}

// ---- conv: implicit GEMM, block = 8h x 16w x 64k, MFMA 16x16x32 bf16 ----
__global__ __launch_bounds__(256) void conv_mfma(const unsigned short* __restrict__ xt,
                                                 const unsigned short* __restrict__ wt,
                                                 const float* __restrict__ bias,
                                                 float* __restrict__ out) {
    __shared__ union {
        struct { unsigned short xs[180 * 72]; unsigned short ws[64 * 72]; } s;
        float co[64 * 132];                       // [k][m 128 + pad4]
    } sm;
    int tid = threadIdx.x;
    int wave = tid >> 6, lane = tid & 63;
    int wl = lane & 15, quad = lane >> 4;
    int w0 = blockIdx.x * 16, h0 = blockIdx.y * 8, n = blockIdx.z;

    // stage halo x-tile: 10h x 18w x 64c bf16, zero-filled OOB
    #pragma unroll
    for (int it = 0; it < 6; ++it) {
        int idx = it * 256 + tid;                 // 1440 uint4 slots
        if (idx < 1440) {
            int pixel = idx >> 3, sub = idx & 7;
            int r = pixel / 18, col = pixel % 18;
            int hh = h0 + r - 1, ww = w0 + col - 1;
            uint4 v = {0u, 0u, 0u, 0u};
            if (hh >= 0 && hh < HW && ww >= 0 && ww < HW)
                v = *(const uint4*)(xt + ((n * HW + hh) * HW + ww) * 64 + sub * 8);
            *(uint4*)&sm.s.xs[pixel * 72 + sub * 8] = v;
        }
    }

    f32x4 zero = {0.f, 0.f, 0.f, 0.f};
    f32x4 acc[2][4];
    #pragma unroll
    for (int mt = 0; mt < 2; ++mt)
        #pragma unroll
        for (int nt = 0; nt < 4; ++nt) acc[mt][nt] = zero;

    int hl_base = wave * 2;
    for (int p = 0; p < 9; ++p) {
        __syncthreads();                          // ws readers of prev iter done (also covers xs writes at p=0)
        #pragma unroll
        for (int it = 0; it < 2; ++it) {          // load 64x64 B-slab (8 KB, L2-hot)
            int idx = it * 256 + tid;
            int k = idx >> 3, sub = idx & 7;
            uint4 v = *(const uint4*)(wt + p * 4096 + k * 64 + sub * 8);
            *(uint4*)&sm.s.ws[k * 72 + sub * 8] = v;
        }
        __syncthreads();
        int dh = p / 3, dw = p % 3;
        #pragma unroll
        for (int cs = 0; cs < 2; ++cs) {
            int cofs = cs * 32 + quad * 8;
            s16x8 bf[4];
            #pragma unroll
            for (int nt = 0; nt < 4; ++nt)
                bf[nt] = *(const s16x8*)&sm.s.ws[(nt * 16 + wl) * 72 + cofs];
            #pragma unroll
            for (int mt = 0; mt < 2; ++mt) {
                int pixel = (hl_base + mt + dh) * 18 + (wl + dw);
                s16x8 af = *(const s16x8*)&sm.s.xs[pixel * 72 + cofs];
                #pragma unroll
                for (int nt = 0; nt < 4; ++nt)
                    acc[mt][nt] = __builtin_amdgcn_mfma_f32_16x16x32_bf16(
                        af, bf[nt], acc[mt][nt], 0, 0, 0);
            }
        }
    }

    // epilogue: acc -> LDS [k][m] -> coalesced NCHW float4 stores
    __syncthreads();
    #pragma unroll
    for (int mt = 0; mt < 2; ++mt) {
        int m0 = wave * 32 + mt * 16 + quad * 4;  // C/D row = quad*4+i
        #pragma unroll
        for (int nt = 0; nt < 4; ++nt) {
            int k = nt * 16 + wl;                 // C/D col = lane&15
            *(f32x4*)&sm.co[k * 132 + m0] = acc[mt][nt];
        }
    }
    __syncthreads();
    int outbase = n * CHW + h0 * HW + w0;
    #pragma unroll
    for (int it = 0; it < 8; ++it) {
        int chunk = it * 256 + tid;               // 2048 float4s
        int k = chunk >> 5, mq = chunk & 31;
        int m0 = mq * 4;
        int hl = m0 >> 4, wlq = m0 & 15;
        f32x4 v = *(const f32x4*)&sm.co[k * 132 + m0];
        float b = bias[k];
        v.x += b; v.y += b; v.z += b; v.w += b;
        *(f32x4*)(out + outbase + k * 12544 + hl * HW + wlq) = v;
    }
}

extern "C" void kernel_launch(void* const* d_in, const int* in_sizes, int n_in,
                              void* d_out, int out_size, void* d_ws, size_t ws_size,
                              hipStream_t stream) {
    const float* x    = (const float*)d_in[0];
    const float* w    = (const float*)d_in[1];
    const float* bias = (const float*)d_in[2];
    float* out = (float*)d_out;
    char* ws = (char*)d_ws;
    unsigned short* xt = (unsigned short*)ws;                       // 51,380,224 B (NHWC bf16)
    unsigned short* wt = (unsigned short*)(ws + 51380224);          //     73,728 B
    float2*         sc = (float2*)(ws + 51380224 + 73728);          //  5,708,920 B

    hipLaunchKernelGGL(q1_scales,    dim3(2788),      dim3(256), 0, stream, x, sc);
    hipLaunchKernelGGL(qw_kernel,    dim3(4),         dim3(256), 0, stream, w, wt);
    hipLaunchKernelGGL(q2_transpose, dim3(112, 32),   dim3(256), 0, stream, x, sc, xt);
    hipLaunchKernelGGL(conv_mfma,    dim3(7, 14, 32), dim3(256), 0, stream, xt, wt, bias, out);
}

// Round 2
// 317.717 us; speedup vs baseline: 1.0518x; 1.0518x over previous
//
#include <hip/hip_runtime.h>
#include <hip/hip_bf16.h>

typedef __attribute__((ext_vector_type(4))) float f32x4;
typedef __attribute__((ext_vector_type(8))) short s16x8;

#define X_ELEMS 25690112          // 32*64*112*112
#define NG_FULL 713614            // X_ELEMS/36 (rem 8)
#define NG      713615
#define HW 112
#define CHW (64*112*112)          // 802816

// q = I * 2^(e-7), |I|<=256 -> exactly representable in bf16; low 16 fp32 bits are 0.
__device__ __forceinline__ unsigned short f32_to_bf16_exact(float q) {
    return (unsigned short)(__float_as_uint(q) >> 16);
}

__device__ __forceinline__ void scale_from_max(float m, float& scale, float& inv) {
    if (m > 0.f) {
        int e = (int)((__float_as_uint(m) >> 23) & 0xFF) - 127;  // exact floor(log2(m)) for normal m
        scale = __builtin_ldexpf(1.0f, e - 7);
        inv   = __builtin_ldexpf(1.0f, 7 - e);
    } else { scale = 0.f; inv = 0.f; }
}

// ---- Q1: per-group (36 consecutive NCHW elems) scale for x ----
__global__ __launch_bounds__(256) void q1_scales(const float* __restrict__ x,
                                                 float2* __restrict__ sc) {
    int g = blockIdx.x * 256 + threadIdx.x;
    if (g >= NG) return;
    const float4* p = (const float4*)x + g * 9;
    float m = 0.f;
    if (g < NG_FULL) {
        #pragma unroll
        for (int i = 0; i < 9; ++i) {
            float4 v = p[i];
            m = fmaxf(m, fmaxf(fmaxf(fabsf(v.x), fabsf(v.y)), fmaxf(fabsf(v.z), fabsf(v.w))));
        }
    } else {
        #pragma unroll
        for (int i = 0; i < 2; ++i) {      // tail group: 8 real elems
            float4 v = p[i];
            m = fmaxf(m, fmaxf(fmaxf(fabsf(v.x), fabsf(v.y)), fmaxf(fabsf(v.z), fabsf(v.w))));
        }
    }
    float s, inv; scale_from_max(m, s, inv);
    sc[g] = make_float2(s, inv);
}

// ---- QW: quantize weight, write [pos=9][k=64][c=64] bf16 ----
__global__ __launch_bounds__(256) void qw_kernel(const float* __restrict__ w,
                                                 unsigned short* __restrict__ wt) {
    int g = blockIdx.x * 256 + threadIdx.x;
    if (g >= 1024) return;                        // 36864/36 = 1024 exact
    const float4* p = (const float4*)w + g * 9;
    float vv[36]; float m = 0.f;
    #pragma unroll
    for (int i = 0; i < 9; ++i) {
        float4 v = p[i];
        vv[i*4+0]=v.x; vv[i*4+1]=v.y; vv[i*4+2]=v.z; vv[i*4+3]=v.w;
        m = fmaxf(m, fmaxf(fmaxf(fabsf(v.x), fabsf(v.y)), fmaxf(fabsf(v.z), fabsf(v.w))));
    }
    float s, inv; scale_from_max(m, s, inv);
    #pragma unroll
    for (int j = 0; j < 36; ++j) {
        int flat = g * 36 + j;
        int k = flat / 576, rem = flat % 576;
        int c = rem / 9, pp = rem % 9;
        float q = rintf(vv[j] * inv) * s;
        wt[pp * 4096 + k * 64 + c] = f32_to_bf16_exact(q);
    }
}

// ---- Q2: quantize x, NCHW -> NHWC bf16, no LDS. Thread owns (w, 32 c's). ----
__global__ __launch_bounds__(256) void q2_quant(const float* __restrict__ x,
                                               const float2* __restrict__ sc,
                                               unsigned short* __restrict__ xt) {
    int n = blockIdx.y, h = blockIdx.x;
    int tid = threadIdx.x;
    int cg = tid >> 7;                 // 0/1 -> c 0-31 / 32-63
    int wv = tid & 127;
    if (wv >= HW) return;
    int base = n * CHW + h * HW + wv;
    int ob = ((n * HW + h) * HW + wv) * 64 + cg * 32;
    #pragma unroll
    for (int jo = 0; jo < 4; ++jo) {
        union { unsigned short u[8]; uint4 d; } pk;
        #pragma unroll
        for (int j = 0; j < 8; ++j) {
            int c = cg * 32 + jo * 8 + j;
            unsigned off = (unsigned)(base + c * 12544);
            float v = x[off];
            float2 s = sc[off / 36u];
            pk.u[j] = f32_to_bf16_exact(rintf(v * s.y) * s.x);
        }
        *(uint4*)(xt + ob + jo * 8) = pk.d;
    }
}

// ---- conv: persistent blocks, tile 8h x 28w x 64k, weights in registers,
// ---- double-buffered halo in LDS, one barrier per tile ----
__global__ __launch_bounds__(256, 1) void conv_mfma(const unsigned short* __restrict__ xt,
                                                    const unsigned short* __restrict__ wt,
                                                    const float* __restrict__ bias,
                                                    float* __restrict__ out) {
    __shared__ unsigned short xs[2][300 * 72];    // 10 rows x 30 cols halo, 72-short pixel stride
    const int tid = threadIdx.x;
    const int wave = tid >> 6, lane = tid & 63;
    const int wl = lane & 15, quad = lane >> 4;
    const int b = blockIdx.x;

    // B fragments resident in registers: [pos][cs][nt], gathered once from L2
    s16x8 Bf[9][2][4];
    #pragma unroll
    for (int p = 0; p < 9; ++p)
        #pragma unroll
        for (int cs = 0; cs < 2; ++cs)
            #pragma unroll
            for (int nt = 0; nt < 4; ++nt)
                Bf[p][cs][nt] = *(const s16x8*)(wt + p * 4096 + (nt * 16 + wl) * 64 + cs * 32 + quad * 8);

    float bv[4];
    #pragma unroll
    for (int nt = 0; nt < 4; ++nt) bv[nt] = bias[nt * 16 + wl];

    // wave m-partition over 14 m-tiles: {4,4,3,3}
    const int ms = (wave < 2) ? wave * 4 : 8 + (wave - 2) * 3;
    const int mc = (wave < 2) ? 4 : 3;

    // per-lane A pixel bases (tile-independent): m = (ms+mti)*16 + wl
    int pixb[4];
    #pragma unroll
    for (int mti = 0; mti < 4; ++mti) {
        int m = (ms + mti) * 16 + wl;
        pixb[mti] = (m / 28) * 30 + (m % 28);
    }
    // epilogue decode (tile-independent): m0 = (ms+mti)*16 + quad*4; 28%4==0 -> float4 within a row
    int eofs[4];
    #pragma unroll
    for (int mti = 0; mti < 4; ++mti) {
        int m0 = (ms + mti) * 16 + quad * 4;
        eofs[mti] = (m0 / 28) * HW + (m0 % 28);
    }

    // stage tile 0 into xs[0]
    {
        int tile = b;
        int n = tile / 56, rem = tile % 56;
        int h0 = (rem >> 2) * 8, w0 = (rem & 3) * 28;
        #pragma unroll
        for (int it = 0; it < 10; ++it) {
            int q = it * 256 + tid;
            if (q < 2400) {
                int pixel = q >> 3, sub = q & 7;
                int r = pixel / 30, col = pixel % 30;
                int hh = h0 + r - 1, ww = w0 + col - 1;
                uint4 v = {0u, 0u, 0u, 0u};
                if (hh >= 0 && hh < HW && ww >= 0 && ww < HW)
                    v = *(const uint4*)(xt + (((n * HW + hh) * HW + ww) << 6) + sub * 8);
                *(uint4*)&xs[0][pixel * 72 + sub * 8] = v;
            }
        }
    }
    __syncthreads();

    for (int t = 0; t < 7; ++t) {
        const int cur = t & 1;
        int tile = b + t * 256;
        int n = tile / 56, rem = tile % 56;
        int h0 = (rem >> 2) * 8, w0 = (rem & 3) * 28;

        // prefetch tile t+1 halo into registers (async, consumed after compute)
        uint4 pf[10];
        if (t < 6) {
            int tile2 = tile + 256;
            int n2 = tile2 / 56, rem2 = tile2 % 56;
            int h02 = (rem2 >> 2) * 8, w02 = (rem2 & 3) * 28;
            #pragma unroll
            for (int it = 0; it < 10; ++it) {
                int q = it * 256 + tid;
                pf[it].x = 0u; pf[it].y = 0u; pf[it].z = 0u; pf[it].w = 0u;
                if (q < 2400) {
                    int pixel = q >> 3, sub = q & 7;
                    int r = pixel / 30, col = pixel % 30;
                    int hh = h02 + r - 1, ww = w02 + col - 1;
                    if (hh >= 0 && hh < HW && ww >= 0 && ww < HW)
                        pf[it] = *(const uint4*)(xt + (((n2 * HW + hh) * HW + ww) << 6) + sub * 8);
                }
            }
        }

        // compute tile t
        f32x4 acc[4][4];
        f32x4 zero = {0.f, 0.f, 0.f, 0.f};
        #pragma unroll
        for (int mti = 0; mti < 4; ++mti)
            #pragma unroll
            for (int nt = 0; nt < 4; ++nt) acc[mti][nt] = zero;

        const unsigned short* xb = xs[cur];
        #pragma unroll
        for (int p = 0; p < 9; ++p) {
            const int dpix = (p / 3) * 30 + (p % 3);
            #pragma unroll
            for (int cs = 0; cs < 2; ++cs) {
                const int cofs = cs * 32 + quad * 8;
                #pragma unroll
                for (int mti = 0; mti < 4; ++mti) {
                    if (mti < mc) {
                        s16x8 A = *(const s16x8*)&xb[(pixb[mti] + dpix) * 72 + cofs];
                        #pragma unroll
                        for (int nt = 0; nt < 4; ++nt)
                            acc[mti][nt] = __builtin_amdgcn_mfma_f32_16x16x32_bf16(
                                A, Bf[p][cs][nt], acc[mti][nt], 0, 0, 0);
                    }
                }
            }
        }

        // epilogue: direct coalesced float4 stores (4 consecutive w per lane)
        int obase = n * CHW + h0 * HW + w0;
        #pragma unroll
        for (int mti = 0; mti < 4; ++mti) {
            if (mti < mc) {
                #pragma unroll
                for (int nt = 0; nt < 4; ++nt) {
                    f32x4 v = acc[mti][nt];
                    v.x += bv[nt]; v.y += bv[nt]; v.z += bv[nt]; v.w += bv[nt];
                    *(f32x4*)(out + obase + (nt * 16 + wl) * 12544 + eofs[mti]) = v;
                }
            }
        }

        // drain prefetch into the other LDS buffer
        if (t < 6) {
            #pragma unroll
            for (int it = 0; it < 10; ++it) {
                int q = it * 256 + tid;
                if (q < 2400) {
                    int pixel = q >> 3, sub = q & 7;
                    *(uint4*)&xs[1 - cur][pixel * 72 + sub * 8] = pf[it];
                }
            }
        }
        __syncthreads();
    }
}

extern "C" void kernel_launch(void* const* d_in, const int* in_sizes, int n_in,
                              void* d_out, int out_size, void* d_ws, size_t ws_size,
                              hipStream_t stream) {
    const float* x    = (const float*)d_in[0];
    const float* w    = (const float*)d_in[1];
    const float* bias = (const float*)d_in[2];
    float* out = (float*)d_out;
    char* ws = (char*)d_ws;
    unsigned short* xt = (unsigned short*)ws;                       // 51,380,224 B (NHWC bf16)
    unsigned short* wt = (unsigned short*)(ws + 51380224);          //     73,728 B
    float2*         sc = (float2*)(ws + 51380224 + 73728);          //  5,708,920 B

    hipLaunchKernelGGL(q1_scales, dim3(2788),    dim3(256), 0, stream, x, sc);
    hipLaunchKernelGGL(qw_kernel, dim3(4),       dim3(256), 0, stream, w, wt);
    hipLaunchKernelGGL(q2_quant,  dim3(112, 32), dim3(256), 0, stream, x, sc, xt);
    hipLaunchKernelGGL(conv_mfma, dim3(256),     dim3(256), 0, stream, xt, wt, bias, out);
}

// Round 3
// 302.495 us; speedup vs baseline: 1.1048x; 1.0503x over previous
//
#include <hip/hip_runtime.h>
#include <hip/hip_bf16.h>

typedef __attribute__((ext_vector_type(4))) float f32x4;
typedef __attribute__((ext_vector_type(8))) short s16x8;

#define X_ELEMS 25690112          // 32*64*112*112
#define X_F4    6422528           // X_ELEMS/4
#define NG_FULL 713614            // X_ELEMS/36 (rem 8)
#define NG      713615
#define HW 112
#define CHW (64*112*112)          // 802816

// q = I * 2^(e-7), |I|<=256 -> exactly representable in bf16; low 16 fp32 bits are 0.
__device__ __forceinline__ unsigned short f32_to_bf16_exact(float q) {
    return (unsigned short)(__float_as_uint(q) >> 16);
}

__device__ __forceinline__ void scale_from_max(float m, float& scale, float& inv) {
    if (m > 0.f) {
        int e = (int)((__float_as_uint(m) >> 23) & 0xFF) - 127;  // exact floor(log2(m)) for normal m
        scale = __builtin_ldexpf(1.0f, e - 7);
        inv   = __builtin_ldexpf(1.0f, 7 - e);
    } else { scale = 0.f; inv = 0.f; }
}

// ---- Q1: per-group (36 elems) scale. Coalesced loads + LDS max staging. ----
// Block handles 256 groups = 9216 floats = 2304 float4 (contiguous).
__global__ __launch_bounds__(256) void q1_scales(const float* __restrict__ x,
                                                 float2* __restrict__ sc) {
    __shared__ float lmax[2304];
    int b = blockIdx.x, tid = threadIdx.x;
    long base4 = (long)b * 2304;
    #pragma unroll
    for (int it = 0; it < 9; ++it) {
        int i = it * 256 + tid;
        long g4 = base4 + i;
        float m = 0.f;
        if (g4 < X_F4) {
            float4 v = ((const float4*)x)[g4];
            m = fmaxf(fmaxf(fabsf(v.x), fabsf(v.y)), fmaxf(fabsf(v.z), fabsf(v.w)));
        }
        lmax[i] = m;
    }
    __syncthreads();
    int g = b * 256 + tid;
    if (g < NG) {
        float m = 0.f;
        int o = tid * 9;                      // stride-9 over 32 banks: 2-way, free
        #pragma unroll
        for (int j = 0; j < 9; ++j) m = fmaxf(m, lmax[o + j]);
        float s, inv; scale_from_max(m, s, inv);
        sc[g] = make_float2(s, inv);
    }
}

// ---- QW: quantize weight, write [pos=9][k=64][c=64] bf16 ----
__global__ __launch_bounds__(256) void qw_kernel(const float* __restrict__ w,
                                                 unsigned short* __restrict__ wt) {
    int g = blockIdx.x * 256 + threadIdx.x;
    if (g >= 1024) return;                        // 36864/36 = 1024 exact
    const float4* p = (const float4*)w + g * 9;
    float vv[36]; float m = 0.f;
    #pragma unroll
    for (int i = 0; i < 9; ++i) {
        float4 v = p[i];
        vv[i*4+0]=v.x; vv[i*4+1]=v.y; vv[i*4+2]=v.z; vv[i*4+3]=v.w;
        m = fmaxf(m, fmaxf(fmaxf(fabsf(v.x), fabsf(v.y)), fmaxf(fabsf(v.z), fabsf(v.w))));
    }
    float s, inv; scale_from_max(m, s, inv);
    #pragma unroll
    for (int j = 0; j < 36; ++j) {
        int flat = g * 36 + j;
        int k = flat / 576, rem = flat % 576;
        int c = rem / 9, pp = rem % 9;
        float q = rintf(vv[j] * inv) * s;
        wt[pp * 4096 + k * 64 + c] = f32_to_bf16_exact(q);
    }
}

// ---- Q2: quantize x, NCHW -> NHWC bf16, no LDS. Thread owns (w, 32 c's). ----
__global__ __launch_bounds__(256) void q2_quant(const float* __restrict__ x,
                                               const float2* __restrict__ sc,
                                               unsigned short* __restrict__ xt) {
    int n = blockIdx.y, h = blockIdx.x;
    int tid = threadIdx.x;
    int cg = tid >> 7;                 // 0/1 -> c 0-31 / 32-63
    int wv = tid & 127;
    if (wv >= HW) return;
    int base = n * CHW + h * HW + wv;
    int ob = ((n * HW + h) * HW + wv) * 64 + cg * 32;
    #pragma unroll
    for (int jo = 0; jo < 4; ++jo) {
        union { unsigned short u[8]; uint4 d; } pk;
        #pragma unroll
        for (int j = 0; j < 8; ++j) {
            int c = cg * 32 + jo * 8 + j;
            unsigned off = (unsigned)(base + c * 12544);
            float v = x[off];
            float2 s = sc[off / 36u];
            pk.u[j] = f32_to_bf16_exact(rintf(v * s.y) * s.x);
        }
        *(uint4*)(xt + ob + jo * 8) = pk.d;
    }
}

// ---- conv: tile 8h x 28w x 64k, one tile/block, grid 1792.
// 4 waves = 2 k-groups x 2 m-groups; per wave: Bf[9][2][2] (144 VGPR) + acc[7][2] (56).
// Single-buffer LDS halo (43.2 KB) -> 2 blocks/CU, one barrier per block. ----
__global__ __launch_bounds__(256, 2) void conv_mfma(const unsigned short* __restrict__ xt,
                                                    const unsigned short* __restrict__ wt,
                                                    const float* __restrict__ bias,
                                                    float* __restrict__ out) {
    __shared__ unsigned short xs[300 * 72];       // 10 rows x 30 cols halo, 72-short pixel stride
    const int tid = threadIdx.x;
    const int wave = tid >> 6, lane = tid & 63;
    const int wl = lane & 15, quad = lane >> 4;
    const int kg = wave & 1, mg = wave >> 1;
    const int b = blockIdx.x;
    const int n = b / 56, rem = b % 56;
    const int h0 = (rem >> 2) * 8, w0 = (rem & 3) * 28;

    // stage halo tile (coalesced uint4), zero-filled OOB
    #pragma unroll
    for (int it = 0; it < 10; ++it) {
        int q = it * 256 + tid;
        if (q < 2400) {
            int pixel = q >> 3, sub = q & 7;
            int r = pixel / 30, col = pixel % 30;
            int hh = h0 + r - 1, ww = w0 + col - 1;
            uint4 v = {0u, 0u, 0u, 0u};
            if (hh >= 0 && hh < HW && ww >= 0 && ww < HW)
                v = *(const uint4*)(xt + (((n * HW + hh) * HW + ww) << 6) + sub * 8);
            *(uint4*)&xs[pixel * 72 + sub * 8] = v;
        }
    }

    // gather this wave's B fragments (32 k-channels): overlaps staging
    s16x8 Bf[9][2][2];
    #pragma unroll
    for (int p = 0; p < 9; ++p)
        #pragma unroll
        for (int cs = 0; cs < 2; ++cs)
            #pragma unroll
            for (int j = 0; j < 2; ++j)
                Bf[p][cs][j] = *(const s16x8*)(wt + p * 4096 +
                                ((kg * 2 + j) * 16 + wl) * 64 + cs * 32 + quad * 8);

    float bv[2];
    #pragma unroll
    for (int j = 0; j < 2; ++j) bv[j] = bias[kg * 32 + j * 16 + wl];

    int pixb[7], eofs[7];
    #pragma unroll
    for (int mti = 0; mti < 7; ++mti) {
        int m = (mg * 7 + mti) * 16 + wl;
        pixb[mti] = (m / 28) * 30 + (m % 28);
        int m0 = (mg * 7 + mti) * 16 + quad * 4;  // 28%4==0 -> float4 stays in-row
        eofs[mti] = (m0 / 28) * HW + (m0 % 28);
    }

    __syncthreads();

    f32x4 acc[7][2];
    f32x4 zero = {0.f, 0.f, 0.f, 0.f};
    #pragma unroll
    for (int mti = 0; mti < 7; ++mti) { acc[mti][0] = zero; acc[mti][1] = zero; }

    #pragma unroll
    for (int p = 0; p < 9; ++p) {
        const int dpix = (p / 3) * 30 + (p % 3);
        #pragma unroll
        for (int cs = 0; cs < 2; ++cs) {
            const int cofs = cs * 32 + quad * 8;
            #pragma unroll
            for (int mti = 0; mti < 7; ++mti) {
                s16x8 A = *(const s16x8*)&xs[(pixb[mti] + dpix) * 72 + cofs];
                acc[mti][0] = __builtin_amdgcn_mfma_f32_16x16x32_bf16(A, Bf[p][cs][0], acc[mti][0], 0, 0, 0);
                acc[mti][1] = __builtin_amdgcn_mfma_f32_16x16x32_bf16(A, Bf[p][cs][1], acc[mti][1], 0, 0, 0);
            }
        }
    }

    // epilogue: direct coalesced float4 stores
    int obase = n * CHW + h0 * HW + w0;
    #pragma unroll
    for (int mti = 0; mti < 7; ++mti) {
        #pragma unroll
        for (int j = 0; j < 2; ++j) {
            f32x4 v = acc[mti][j];
            v.x += bv[j]; v.y += bv[j]; v.z += bv[j]; v.w += bv[j];
            *(f32x4*)(out + obase + (kg * 32 + j * 16 + wl) * 12544 + eofs[mti]) = v;
        }
    }
}

extern "C" void kernel_launch(void* const* d_in, const int* in_sizes, int n_in,
                              void* d_out, int out_size, void* d_ws, size_t ws_size,
                              hipStream_t stream) {
    const float* x    = (const float*)d_in[0];
    const float* w    = (const float*)d_in[1];
    const float* bias = (const float*)d_in[2];
    float* out = (float*)d_out;
    char* ws = (char*)d_ws;
    unsigned short* xt = (unsigned short*)ws;                       // 51,380,224 B (NHWC bf16)
    unsigned short* wt = (unsigned short*)(ws + 51380224);          //     73,728 B
    float2*         sc = (float2*)(ws + 51380224 + 73728);          //  5,708,920 B

    hipLaunchKernelGGL(q1_scales, dim3(2788),    dim3(256), 0, stream, x, sc);
    hipLaunchKernelGGL(qw_kernel, dim3(4),       dim3(256), 0, stream, w, wt);
    hipLaunchKernelGGL(q2_quant,  dim3(112, 32), dim3(256), 0, stream, x, sc, xt);
    hipLaunchKernelGGL(conv_mfma, dim3(1792),    dim3(256), 0, stream, xt, wt, bias, out);
}